// Round 5
// baseline (486.813 us; speedup 1.0000x reference)
//
#include <hip/hip_runtime.h>
#include <hip/hip_bf16.h>

#define NN 100000
#define DD 64
#define EE 400000
#define TT 5

#define CH 16                    /* coarse src buckets (chunks) */
#define BPC 6250                 /* NN/CH exact */
#define PSPLIT 32                /* partition slices per t */
#define PESL (EE / PSPLIT)       /* 12,500 edges per slice */
#define PBN (TT * CH * PSPLIT)   /* 2560 partition counters */
#define PB_IDX(t, c, s) ((((t) * CH + (c)) * PSPLIT) + (s))

#define SCAN_TOTAL 500000        /* T*N bins */
#define SCAN_T 256
#define SCAN_PER 1024            /* bins per scan block */
#define SCAN_B 512               /* 512*1024 >= 500000 */

#define NB 64                    /* nodes per k_edge4 block (exclusive ownership) */
#define NBLK ((NN + NB - 1) / NB)   /* 1563 */

typedef __bf16 bf16x8 __attribute__((ext_vector_type(8)));
typedef float  f32x4  __attribute__((ext_vector_type(4)));

// ws layout (bytes) — total 40,914,240 (unchanged envelope)
#define OFF_XBF  0u            // N*D ushort      = 12,800,000
#define OFF_WT   12800000u     // T*64*128 ushort = 81,920
#define OFF_CTOT 12881920u     // T*N u32 (cnt_tot) = 2,000,000
#define OFF_WGT  14881920u     // T f32 (pad 64)
#define OFF_CUR  14881984u     // T*N u32 (scan of totals) = 2,000,000
#define OFF_BS   16881984u     // 512 u32 (pad 2048)
#define OFF_BO   16884032u     // 512 u32 (pad 2048)
#define OFF_PE   16886080u     // 2M u32 packed (src_local<<17|dst) = 8,000,000
#define OFF_PB   24886080u     // 2561 u32 partition scan (10,244 B)
#define OFF_DST  24914240u     // 2M int (sorted dst) = 8,000,000
#define OFF_SEG  32914240u     // 2M int (seg src)    = 8,000,000 -> 40,914,240

__device__ __forceinline__ unsigned short f2bf(float f) {
    union { float f; unsigned u; } v; v.f = f;
    unsigned u = v.u;
    return (unsigned short)((u + 0x7FFFu + ((u >> 16) & 1u)) >> 16);  // RNE
}

// ---------------- Phase 1: convert (no out-zero: k_edge4 writes every out
// line exactly once, non-atomically) ------------------------------------------
__global__ void k_init(const float* __restrict__ x, const float* __restrict__ W,
                       const float* __restrict__ ea,
                       unsigned short* __restrict__ xbf, unsigned short* __restrict__ wT,
                       float* __restrict__ wgt) {
    int i = blockIdx.x * blockDim.x + threadIdx.x;   // grid covers N*D exactly
    if (i < NN * DD) {
        xbf[i] = f2bf(x[i]);
    }
    if (i < TT * 128 * 64) {
        int t = i >> 13;          // /8192
        int rem = i & 8191;
        int d = rem >> 7;         // /128
        int k = rem & 127;
        wT[i] = f2bf(W[t * 8192 + k * 64 + d]);   // wT[t][d][k] = W[t][k][d]
    }
    if (i == 0) {
        float m = -1e30f;
        for (int t = 0; t < TT; t++) m = fmaxf(m, ea[t]);
        float e[TT]; float s = 0.0f;
        for (int t = 0; t < TT; t++) { e[t] = __expf(ea[t] - m); s += e[t]; }
        for (int t = 0; t < TT; t++) wgt[t] = e[t] / s;
    }
}

// ---------------- Phase 2a: coarse 16-bucket counts per (slice, t) -----------
__global__ __launch_bounds__(256) void k_pcount(const int* __restrict__ edges,
                                                unsigned* __restrict__ pcnt) {
    const int s = blockIdx.x, t = blockIdx.y;
    __shared__ unsigned h[CH];
    if (threadIdx.x < CH) h[threadIdx.x] = 0u;
    __syncthreads();
    const int4* srcp = reinterpret_cast<const int4*>(edges + (size_t)t * 2 * EE + s * PESL);
    for (int i = threadIdx.x; i < PESL / 4; i += 256) {
        int4 v = srcp[i];
        atomicAdd(&h[(unsigned)v.x / BPC], 1u);
        atomicAdd(&h[(unsigned)v.y / BPC], 1u);
        atomicAdd(&h[(unsigned)v.z / BPC], 1u);
        atomicAdd(&h[(unsigned)v.w / BPC], 1u);
    }
    __syncthreads();
    if (threadIdx.x < CH) pcnt[PB_IDX(t, threadIdx.x, s)] = h[threadIdx.x];
}

// ---------------- Phase 2b: exclusive scan of 2560 partition counters --------
__global__ void k_pscan(unsigned* __restrict__ pb) {
    __shared__ unsigned s[256];
    const int tid = threadIdx.x;
    unsigned v[10]; unsigned sum = 0u;
#pragma unroll
    for (int j = 0; j < 10; j++) { v[j] = pb[tid * 10 + j]; sum += v[j]; }
    s[tid] = sum;
    __syncthreads();
    unsigned inc = sum;
    for (int d = 1; d < 256; d <<= 1) {
        unsigned a = (tid >= d) ? s[tid - d] : 0u;
        __syncthreads();
        inc += a;
        s[tid] = inc;
        __syncthreads();
    }
    unsigned run = inc - sum;
#pragma unroll
    for (int j = 0; j < 10; j++) { unsigned c = v[j]; pb[tid * 10 + j] = run; run += c; }
    if (tid == 255) pb[PBN] = run;   // sentinel = 2,000,000
}

// ---------------- Phase 2c: partition scatter, (src_local:13 | dst:17) -------
__global__ __launch_bounds__(256) void k_pscat(const int* __restrict__ edges,
                                               const unsigned* __restrict__ pbase,
                                               unsigned* __restrict__ pe) {
    const int s = blockIdx.x, t = blockIdx.y;
    __shared__ unsigned lofs[CH];
    if (threadIdx.x < CH) lofs[threadIdx.x] = pbase[PB_IDX(t, threadIdx.x, s)];
    __syncthreads();
    const int* srcp = edges + (size_t)t * 2 * EE + s * PESL;
    const int* dstp = srcp + EE;
    for (int i = threadIdx.x; i < PESL / 4; i += 256) {
        int4 v = reinterpret_cast<const int4*>(srcp)[i];
        int4 w = reinterpret_cast<const int4*>(dstp)[i];
        {
            unsigned c = (unsigned)v.x / BPC;
            unsigned o = atomicAdd(&lofs[c], 1u);
            pe[o] = (((unsigned)v.x - c * BPC) << 17) | (unsigned)w.x;
        }
        {
            unsigned c = (unsigned)v.y / BPC;
            unsigned o = atomicAdd(&lofs[c], 1u);
            pe[o] = (((unsigned)v.y - c * BPC) << 17) | (unsigned)w.y;
        }
        {
            unsigned c = (unsigned)v.z / BPC;
            unsigned o = atomicAdd(&lofs[c], 1u);
            pe[o] = (((unsigned)v.z - c * BPC) << 17) | (unsigned)w.z;
        }
        {
            unsigned c = (unsigned)v.w / BPC;
            unsigned o = atomicAdd(&lofs[c], 1u);
            pe[o] = (((unsigned)v.w - c * BPC) << 17) | (unsigned)w.w;
        }
    }
}

// ---------------- Phase 2d: exact per-src counts from bucketed pe ------------
__global__ __launch_bounds__(512) void k_bcount(const unsigned* __restrict__ pe,
                                                const unsigned* __restrict__ pbase,
                                                unsigned* __restrict__ cnt_tot) {
    const int c = blockIdx.x, t = blockIdx.y;
    __shared__ unsigned h[BPC];
    for (int i = threadIdx.x; i < BPC; i += 512) h[i] = 0u;
    __syncthreads();
    const unsigned st = pbase[PB_IDX(t, c, 0)];
    const unsigned en = pbase[((t * CH + c) + 1) * PSPLIT];
    for (unsigned i = st + threadIdx.x; i < en; i += 512)
        atomicAdd(&h[pe[i] >> 17], 1u);
    __syncthreads();
    unsigned* outp = cnt_tot + t * NN + c * BPC;
    for (int i = threadIdx.x; i < BPC; i += 512) outp[i] = h[i];
}

// ---------------- Phase 2e: global exclusive scan over T*N bins --------------
__global__ void k_scan1(const unsigned* __restrict__ cnt_tot,
                        unsigned* __restrict__ cur, unsigned* __restrict__ bsum) {
    __shared__ unsigned s[SCAN_T];
    const int b = blockIdx.x, tid = threadIdx.x;
    const int base = b * SCAN_PER + tid * 4;
    unsigned tot[4] = {0u, 0u, 0u, 0u};
    if (base < SCAN_TOTAL) {
        uint4 tv = *reinterpret_cast<const uint4*>(cnt_tot + base);
        tot[0] = tv.x; tot[1] = tv.y; tot[2] = tv.z; tot[3] = tv.w;
    }
    const unsigned tsum = tot[0] + tot[1] + tot[2] + tot[3];
    s[tid] = tsum;
    __syncthreads();
    unsigned inc = tsum;
    for (int d = 1; d < SCAN_T; d <<= 1) {
        unsigned add = (tid >= d) ? s[tid - d] : 0u;
        __syncthreads();
        inc += add;
        s[tid] = inc;
        __syncthreads();
    }
    if (tid == SCAN_T - 1) bsum[b] = inc;
    const unsigned p0 = inc - tsum;
    if (base < SCAN_TOTAL) {
        *reinterpret_cast<uint4*>(cur + base) =
            make_uint4(p0, p0 + tot[0], p0 + tot[0] + tot[1], p0 + tot[0] + tot[1] + tot[2]);
    }
}

__global__ void k_scan2(const unsigned* __restrict__ bsum, unsigned* __restrict__ boff) {
    __shared__ unsigned s[SCAN_B];
    const int tid = threadIdx.x;
    const unsigned v = bsum[tid];
    s[tid] = v;
    __syncthreads();
    unsigned inc = v;
    for (int d = 1; d < SCAN_B; d <<= 1) {
        unsigned add = (tid >= d) ? s[tid - d] : 0u;
        __syncthreads();
        inc += add;
        s[tid] = inc;
        __syncthreads();
    }
    boff[tid] = inc - v;
}

// ---------------- Phase 2f: counting-sort fill + fused seg write -------------
__global__ __launch_bounds__(512) void k_bfill(const unsigned* __restrict__ pe,
                                               const unsigned* __restrict__ pbase,
                                               const unsigned* __restrict__ cur,
                                               const unsigned* __restrict__ boff,
                                               const unsigned* __restrict__ cnt_tot,
                                               int* __restrict__ sdst,
                                               int* __restrict__ seg) {
    const int c = blockIdx.x, t = blockIdx.y;
    __shared__ unsigned curl[BPC];
    const int n0 = c * BPC;
    for (int i = threadIdx.x; i < BPC; i += 512) {
        int g = t * NN + n0 + i;
        unsigned start = cur[g] + boff[g >> 10];
        curl[i] = start;
        unsigned cc = cnt_tot[g];
        int node = n0 + i;
        for (unsigned j = 0; j < cc; j++) seg[start + j] = node;
    }
    __syncthreads();
    const unsigned st = pbase[PB_IDX(t, c, 0)];
    const unsigned en = pbase[((t * CH + c) + 1) * PSPLIT];
    for (unsigned i = st + threadIdx.x; i < en; i += 512) {
        unsigned p = pe[i];
        sdst[atomicAdd(&curl[p >> 17], 1u)] = (int)(p & 0x1FFFFu);
    }
}

// ---------------- Phase 3 (v4): node-exclusive blocks, wave-independent
// 32-edge windows across ALL t. R1's ownership (kills 240 MB of out atomic
// RMW traffic) + R0's wave-level TLP (the hot loop has ZERO barriers — R1's
// failure was block-serial tiles). Each of 4 waves pops windows k=wv,wv+4,...
// from the block's concatenated per-t spans; Ab rows / src_s / scale_s slices
// are wave-private; cross-wave accumulation = LDS ds_add_f32 into accs
// (wave-uniform row + lane-consecutive cols = 2-way bank alias, free).
// No scopes, no queues, no hwregs — plain __syncthreads at entry/exit only. --
__global__ __launch_bounds__(256) void k_edge4(
    const unsigned short* __restrict__ xbf, const unsigned short* __restrict__ wT,
    const float* __restrict__ b, const int* __restrict__ sdst,
    const int* __restrict__ seg, const unsigned* __restrict__ cnt,
    const unsigned* __restrict__ cur, const unsigned* __restrict__ boff,
    const float* __restrict__ wgt, float* __restrict__ out) {

    const int n0 = blockIdx.x * NB;
    const int n1 = (n0 + NB < NN) ? (n0 + NB) : NN;
    const int tid = threadIdx.x;
    const int wv = tid >> 6, lane = tid & 63;
    const int m16 = lane & 15, quad = lane >> 4;

    __shared__ __align__(16) unsigned short Ab[128][136];  // feats; reused as f32 proj[128][68]
    __shared__ __align__(16) float accs[NB][64];           // exclusive node accumulators
    __shared__ float scale_s[128];
    __shared__ int   src_s[132];

    {   // zero accumulators
        float4* a4 = reinterpret_cast<float4*>(&accs[0][0]);
        for (int i = tid; i < NB * 16; i += 256) a4[i] = make_float4(0.f, 0.f, 0.f, 0.f);
    }

    // per-t sorted-edge spans (computed redundantly per thread; registers only,
    // all later accesses via constant-index unrolled loops — rule #20)
    unsigned p0t[TT], p1t[TT];
    int nw[TT], NW = 0;
#pragma unroll
    for (int t = 0; t < TT; t++) {
        int g0 = t * NN + n0;
        int g1 = t * NN + n1;
        unsigned p0 = cur[g0] + boff[g0 >> 10];
        unsigned p1 = (g1 >= SCAN_TOTAL) ? (unsigned)(TT * EE)
                                         : (cur[g1] + boff[g1 >> 10]);
        p0t[t] = p0; p1t[t] = p1;
        nw[t] = (int)((p1 - p0 + 31u) >> 5);
        NW += nw[t];
    }

    __syncthreads();   // accs zero visible to all waves

    for (int k = wv; k < NW; k += 4) {
        // resolve window k -> (t, ts, rows); k is wave-uniform, branches uniform
        int t = 0, rem = k;
#pragma unroll
        for (int tt = 0; tt < TT - 1; tt++)
            if (t == tt && rem >= nw[tt]) { rem -= nw[tt]; t = tt + 1; }
        unsigned p0s = p0t[0], p1s = p1t[0];
#pragma unroll
        for (int tt = 1; tt < TT; tt++)
            if (t == tt) { p0s = p0t[tt]; p1s = p1t[tt]; }
        const unsigned ts = p0s + ((unsigned)rem << 5);
        const unsigned left = p1s - ts;
        const int rows = (int)((left < 32u) ? left : 32u);
        const float wgt_t = wgt[t];

        // gather: lane pair per edge, wave-private Ab rows [wv*32, wv*32+32)
        {
            const int e = lane >> 1, half = lane & 1;
            const int r = wv * 32 + e;
            float4* l = reinterpret_cast<float4*>(&Ab[r][half * 64]);
            if (e < rows) {
                const unsigned pos = ts + (unsigned)e;
                const int idx = half ? sdst[pos] : seg[pos];
                const float4* g = reinterpret_cast<const float4*>(xbf + (size_t)idx * 64);
#pragma unroll
                for (int cc = 0; cc < 8; cc++) l[cc] = g[cc];
                if (half == 0) {
                    src_s[r] = idx - n0;                            // in [0, NB)
                    scale_s[r] = wgt_t / (float)cnt[t * NN + idx];  // cnt>=1 here
                }
            } else {
                const float4 z = make_float4(0.f, 0.f, 0.f, 0.f);
#pragma unroll
                for (int cc = 0; cc < 8; cc++) l[cc] = z;
                if (half == 0) { src_s[r] = 0; scale_s[r] = 0.f; }  // pad adds 0
            }
        }
        // no barrier: same-wave LDS write->read ordered by lgkmcnt

        const unsigned short* wrow = wT + (size_t)t * 8192;   // [d][k], 64x128

        f32x4 acc[2][4];
#pragma unroll
        for (int tm = 0; tm < 2; tm++)
#pragma unroll
            for (int tn = 0; tn < 4; tn++)
                acc[tm][tn] = (f32x4){0.f, 0.f, 0.f, 0.f};

#pragma unroll
        for (int kk = 0; kk < 128; kk += 32) {
            const int kb = kk + quad * 8;
            bf16x8 af[2], bfr[4];
#pragma unroll
            for (int tm = 0; tm < 2; tm++)
                af[tm] = *reinterpret_cast<const bf16x8*>(&Ab[wv * 32 + tm * 16 + m16][kb]);
#pragma unroll
            for (int tn = 0; tn < 4; tn++)
                bfr[tn] = *reinterpret_cast<const bf16x8*>(wrow + (tn * 16 + m16) * 128 + kb);
#pragma unroll
            for (int tm = 0; tm < 2; tm++)
#pragma unroll
                for (int tn = 0; tn < 4; tn++)
                    acc[tm][tn] = __builtin_amdgcn_mfma_f32_16x16x32_bf16(
                        af[tm], bfr[tn], acc[tm][tn], 0, 0, 0);
        }

        float bias[4];
#pragma unroll
        for (int tn = 0; tn < 4; tn++) bias[tn] = b[t * 64 + tn * 16 + m16];

        // scale + relu -> proj (wave-private rows)
        float* proj = reinterpret_cast<float*>(&Ab[0][0]);   // [128][68] f32
#pragma unroll
        for (int tm = 0; tm < 2; tm++) {
#pragma unroll
            for (int r = 0; r < 4; r++) {
                const int eloc = wv * 32 + tm * 16 + quad * 4 + r;
                const float s = scale_s[eloc];
#pragma unroll
                for (int tn = 0; tn < 4; tn++) {
                    float v = acc[tm][tn][r] + bias[tn];
                    v = v > 0.f ? v : 0.f;
                    proj[eloc * 68 + tn * 16 + m16] = v * s;
                }
            }
        }

        // wave-cooperative segmented reduce -> LDS accumulators (ds_add_f32;
        // wave-uniform row, lane-consecutive cols: 2-way alias = free)
        {
            const int j0 = wv * 32;
            float sum = 0.f;
#pragma unroll
            for (int j = j0; j < j0 + 32; j++) {
                sum += proj[j * 68 + lane];
                const bool flush = (j == j0 + 31) || (src_s[j + 1] != src_s[j]);
                if (flush) {
                    atomicAdd(&accs[src_s[j]][lane], sum);
                    sum = 0.f;
                }
            }
        }
    }

    __syncthreads();
    // single coalesced, non-atomic write of the block's exclusive out region
    {
        const int rows = n1 - n0;
        const float4* a4 = reinterpret_cast<const float4*>(&accs[0][0]);
        float4* o4 = reinterpret_cast<float4*>(out + (size_t)n0 * 64);
        for (int i = tid; i < rows * 16; i += 256) o4[i] = a4[i];
    }
}

extern "C" void kernel_launch(void* const* d_in, const int* in_sizes, int n_in,
                              void* d_out, int out_size, void* d_ws, size_t ws_size,
                              hipStream_t stream) {
    const float* x     = (const float*)d_in[0];
    const float* W     = (const float*)d_in[1];
    const float* b     = (const float*)d_in[2];
    const float* ea    = (const float*)d_in[3];
    const int*   edges = (const int*)d_in[4];
    float* out = (float*)d_out;

    char* ws = (char*)d_ws;
    unsigned short* xbf  = (unsigned short*)(ws + OFF_XBF);
    unsigned short* wT   = (unsigned short*)(ws + OFF_WT);
    unsigned* cnt_tot    = (unsigned*)(ws + OFF_CTOT);
    float* wgt           = (float*)(ws + OFF_WGT);
    unsigned* cur        = (unsigned*)(ws + OFF_CUR);
    unsigned* bsum       = (unsigned*)(ws + OFF_BS);
    unsigned* boff       = (unsigned*)(ws + OFF_BO);
    unsigned* pe         = (unsigned*)(ws + OFF_PE);
    unsigned* pb         = (unsigned*)(ws + OFF_PB);
    int* sdst            = (int*)(ws + OFF_DST);
    int* seg             = (int*)(ws + OFF_SEG);

    // Phase 1: x->bf16, W^T, softmax
    k_init<<<(NN * DD) / 256, 256, 0, stream>>>(x, W, ea, xbf, wT, wgt);

    // Phase 2: single-read partition sort (R2, proven 155 us)
    k_pcount<<<dim3(PSPLIT, TT), 256, 0, stream>>>(edges, pb);
    k_pscan<<<1, 256, 0, stream>>>(pb);
    k_pscat<<<dim3(PSPLIT, TT), 256, 0, stream>>>(edges, pb, pe);
    k_bcount<<<dim3(CH, TT), 512, 0, stream>>>(pe, pb, cnt_tot);
    k_scan1<<<SCAN_B, SCAN_T, 0, stream>>>(cnt_tot, cur, bsum);
    k_scan2<<<1, SCAN_B, 0, stream>>>(bsum, boff);
    k_bfill<<<dim3(CH, TT), 512, 0, stream>>>(pe, pb, cur, boff, cnt_tot, sdst, seg);

    // Phase 3: node-exclusive, wave-independent MFMA gather-GEMM; atomic-free out
    k_edge4<<<NBLK, 256, 0, stream>>>(xbf, wT, b, sdst, seg, cnt_tot,
                                      cur, boff, wgt, out);
}

// Round 6
// 418.681 us; speedup vs baseline: 1.1627x; 1.1627x over previous
//
#include <hip/hip_runtime.h>
#include <hip/hip_bf16.h>

#define NN 100000
#define DD 64
#define EE 400000
#define TT 5

#define CH 40                    /* coarse src buckets (chunks) */
#define BPC 2500                 /* NN/CH exact */
#define PSPLIT 32                /* partition slices per t */
#define PESL (EE / PSPLIT)       /* 12,500 edges per slice */
#define PBN (TT * CH * PSPLIT)   /* 6400 partition counters */
#define PB_IDX(t, c, s) ((((t) * CH + (c)) * PSPLIT) + (s))

#define SCAN_TOTAL 500000        /* T*N bins */
#define SCAN_T 256
#define SCAN_PER 1024            /* bins per scan block */
#define SCAN_B 512               /* 512*1024 >= 500000 */

typedef __bf16 bf16x8 __attribute__((ext_vector_type(8)));
typedef float  f32x4  __attribute__((ext_vector_type(4)));

// ws layout (bytes) — total 40,914,240 (unchanged envelope)
#define OFF_XBF  0u            // N*D ushort      = 12,800,000
#define OFF_WT   12800000u     // T*64*128 ushort = 81,920
#define OFF_CTOT 12881920u     // T*N u32 (cnt_tot) = 2,000,000
#define OFF_WGT  14881920u     // T f32 (pad 64)
#define OFF_CUR  14881984u     // T*N u32 (scan of totals) = 2,000,000
#define OFF_BS   16881984u     // 512 u32 (pad 2048)
#define OFF_BO   16884032u     // 512 u32 (pad 2048)
#define OFF_PE   16886080u     // 2M u32 packed (src_local<<17|dst) = 8,000,000
#define OFF_PB   24886080u     // 6401 u32 partition scan (25,604 B < 28,160 slack)
#define OFF_DST  24914240u     // 2M int (sorted dst) = 8,000,000
#define OFF_SEG  32914240u     // 2M int (seg src)    = 8,000,000 -> 40,914,240

__device__ __forceinline__ unsigned short f2bf(float f) {
    union { float f; unsigned u; } v; v.f = f;
    unsigned u = v.u;
    return (unsigned short)((u + 0x7FFFu + ((u >> 16) & 1u)) >> 16);  // RNE
}

// ---------------- Phase 1: init / convert / out-zero (k_edge5 atomics) ------
__global__ void k_init(const float* __restrict__ x, const float* __restrict__ W,
                       const float* __restrict__ ea,
                       unsigned short* __restrict__ xbf, unsigned short* __restrict__ wT,
                       float* __restrict__ wgt, float* __restrict__ out) {
    int i = blockIdx.x * blockDim.x + threadIdx.x;   // grid covers N*D exactly
    if (i < NN * DD) {
        out[i] = 0.0f;
        xbf[i] = f2bf(x[i]);
    }
    if (i < TT * 128 * 64) {
        int t = i >> 13;          // /8192
        int rem = i & 8191;
        int d = rem >> 7;         // /128
        int k = rem & 127;
        wT[i] = f2bf(W[t * 8192 + k * 64 + d]);   // wT[t][d][k] = W[t][k][d]
    }
    if (i == 0) {
        float m = -1e30f;
        for (int t = 0; t < TT; t++) m = fmaxf(m, ea[t]);
        float e[TT]; float s = 0.0f;
        for (int t = 0; t < TT; t++) { e[t] = __expf(ea[t] - m); s += e[t]; }
        for (int t = 0; t < TT; t++) wgt[t] = e[t] / s;
    }
}

// ---------------- Phase 2a: coarse 40-bucket counts per (slice, t) -----------
__global__ __launch_bounds__(256) void k_pcount(const int* __restrict__ edges,
                                                unsigned* __restrict__ pcnt) {
    const int s = blockIdx.x, t = blockIdx.y;
    __shared__ unsigned h[CH];
    if (threadIdx.x < CH) h[threadIdx.x] = 0u;
    __syncthreads();
    const int4* srcp = reinterpret_cast<const int4*>(edges + (size_t)t * 2 * EE + s * PESL);
    for (int i = threadIdx.x; i < PESL / 4; i += 256) {
        int4 v = srcp[i];
        atomicAdd(&h[(unsigned)v.x / BPC], 1u);
        atomicAdd(&h[(unsigned)v.y / BPC], 1u);
        atomicAdd(&h[(unsigned)v.z / BPC], 1u);
        atomicAdd(&h[(unsigned)v.w / BPC], 1u);
    }
    __syncthreads();
    if (threadIdx.x < CH) pcnt[PB_IDX(t, threadIdx.x, s)] = h[threadIdx.x];
}

// ---------------- Phase 2b: exclusive scan of 6400 partition counters --------
__global__ void k_pscan(unsigned* __restrict__ pb) {
    __shared__ unsigned s[512];
    const int tid = threadIdx.x;
    unsigned v[13]; unsigned sum = 0u;
#pragma unroll
    for (int j = 0; j < 13; j++) {
        int g = tid * 13 + j;
        v[j] = (g < PBN) ? pb[g] : 0u;
        sum += v[j];
    }
    s[tid] = sum;
    __syncthreads();
    unsigned inc = sum;
    for (int d = 1; d < 512; d <<= 1) {
        unsigned a = (tid >= d) ? s[tid - d] : 0u;
        __syncthreads();
        inc += a;
        s[tid] = inc;
        __syncthreads();
    }
    unsigned run = inc - sum;
#pragma unroll
    for (int j = 0; j < 13; j++) {
        int g = tid * 13 + j;
        if (g < PBN) pb[g] = run;
        run += v[j];
    }
    if (tid == 511) pb[PBN] = run;   // sentinel = 2,000,000
}

// ---------------- Phase 2c: partition scatter, (src_local:12 | dst:17) -------
__global__ __launch_bounds__(256) void k_pscat(const int* __restrict__ edges,
                                               const unsigned* __restrict__ pbase,
                                               unsigned* __restrict__ pe) {
    const int s = blockIdx.x, t = blockIdx.y;
    __shared__ unsigned lofs[CH];
    if (threadIdx.x < CH) lofs[threadIdx.x] = pbase[PB_IDX(t, threadIdx.x, s)];
    __syncthreads();
    const int* srcp = edges + (size_t)t * 2 * EE + s * PESL;
    const int* dstp = srcp + EE;
    for (int i = threadIdx.x; i < PESL / 4; i += 256) {
        int4 v = reinterpret_cast<const int4*>(srcp)[i];
        int4 w = reinterpret_cast<const int4*>(dstp)[i];
        {
            unsigned c = (unsigned)v.x / BPC;
            unsigned o = atomicAdd(&lofs[c], 1u);
            pe[o] = (((unsigned)v.x - c * BPC) << 17) | (unsigned)w.x;
        }
        {
            unsigned c = (unsigned)v.y / BPC;
            unsigned o = atomicAdd(&lofs[c], 1u);
            pe[o] = (((unsigned)v.y - c * BPC) << 17) | (unsigned)w.y;
        }
        {
            unsigned c = (unsigned)v.z / BPC;
            unsigned o = atomicAdd(&lofs[c], 1u);
            pe[o] = (((unsigned)v.z - c * BPC) << 17) | (unsigned)w.z;
        }
        {
            unsigned c = (unsigned)v.w / BPC;
            unsigned o = atomicAdd(&lofs[c], 1u);
            pe[o] = (((unsigned)v.w - c * BPC) << 17) | (unsigned)w.w;
        }
    }
}

// ---------------- Phase 2d: exact per-src counts from bucketed pe ------------
__global__ __launch_bounds__(512) void k_bcount(const unsigned* __restrict__ pe,
                                                const unsigned* __restrict__ pbase,
                                                unsigned* __restrict__ cnt_tot) {
    const int c = blockIdx.x, t = blockIdx.y;
    __shared__ unsigned h[BPC];
    for (int i = threadIdx.x; i < BPC; i += 512) h[i] = 0u;
    __syncthreads();
    const unsigned st = pbase[PB_IDX(t, c, 0)];
    const unsigned en = pbase[((t * CH + c) + 1) * PSPLIT];
    for (unsigned i = st + threadIdx.x; i < en; i += 512)
        atomicAdd(&h[pe[i] >> 17], 1u);
    __syncthreads();
    unsigned* outp = cnt_tot + t * NN + c * BPC;
    for (int i = threadIdx.x; i < BPC; i += 512) outp[i] = h[i];
}

// ---------------- Phase 2e: global exclusive scan over T*N bins --------------
__global__ void k_scan1(const unsigned* __restrict__ cnt_tot,
                        unsigned* __restrict__ cur, unsigned* __restrict__ bsum) {
    __shared__ unsigned s[SCAN_T];
    const int b = blockIdx.x, tid = threadIdx.x;
    const int base = b * SCAN_PER + tid * 4;
    unsigned tot[4] = {0u, 0u, 0u, 0u};
    if (base < SCAN_TOTAL) {
        uint4 tv = *reinterpret_cast<const uint4*>(cnt_tot + base);
        tot[0] = tv.x; tot[1] = tv.y; tot[2] = tv.z; tot[3] = tv.w;
    }
    const unsigned tsum = tot[0] + tot[1] + tot[2] + tot[3];
    s[tid] = tsum;
    __syncthreads();
    unsigned inc = tsum;
    for (int d = 1; d < SCAN_T; d <<= 1) {
        unsigned add = (tid >= d) ? s[tid - d] : 0u;
        __syncthreads();
        inc += add;
        s[tid] = inc;
        __syncthreads();
    }
    if (tid == SCAN_T - 1) bsum[b] = inc;
    const unsigned p0 = inc - tsum;
    if (base < SCAN_TOTAL) {
        *reinterpret_cast<uint4*>(cur + base) =
            make_uint4(p0, p0 + tot[0], p0 + tot[0] + tot[1], p0 + tot[0] + tot[1] + tot[2]);
    }
}

__global__ void k_scan2(const unsigned* __restrict__ bsum, unsigned* __restrict__ boff) {
    __shared__ unsigned s[SCAN_B];
    const int tid = threadIdx.x;
    const unsigned v = bsum[tid];
    s[tid] = v;
    __syncthreads();
    unsigned inc = v;
    for (int d = 1; d < SCAN_B; d <<= 1) {
        unsigned add = (tid >= d) ? s[tid - d] : 0u;
        __syncthreads();
        inc += add;
        s[tid] = inc;
        __syncthreads();
    }
    boff[tid] = inc - v;
}

// ---------------- Phase 2f: counting-sort fill + fused seg write -------------
__global__ __launch_bounds__(512) void k_bfill(const unsigned* __restrict__ pe,
                                               const unsigned* __restrict__ pbase,
                                               const unsigned* __restrict__ cur,
                                               const unsigned* __restrict__ boff,
                                               const unsigned* __restrict__ cnt_tot,
                                               int* __restrict__ sdst,
                                               int* __restrict__ seg) {
    const int c = blockIdx.x, t = blockIdx.y;
    __shared__ unsigned curl[BPC];
    const int n0 = c * BPC;
    for (int i = threadIdx.x; i < BPC; i += 512) {
        int g = t * NN + n0 + i;
        unsigned start = cur[g] + boff[g >> 10];
        curl[i] = start;
        unsigned cc = cnt_tot[g];
        int node = n0 + i;
        for (unsigned j = 0; j < cc; j++) seg[start + j] = node;
    }
    __syncthreads();
    const unsigned st = pbase[PB_IDX(t, c, 0)];
    const unsigned en = pbase[((t * CH + c) + 1) * PSPLIT];
    for (unsigned i = st + threadIdx.x; i < en; i += 512) {
        unsigned p = pe[i];
        sdst[atomicAdd(&curl[p >> 17], 1u)] = (int)(p & 0x1FFFFu);
    }
}

// ---------------- Phase 3 (v5): barrier-free direct-fragment gather GEMM.
// R5 proved phase 3 is latency-bound: dur ∝ chain / resident-waves (340/184 ≈
// occupancy ratio). So: (1) 16-row waves, 64-edge tiles — acc halves to 16
// VGPRs, __launch_bounds__(256,8) targets VGPR<=64 for 8 waves/SIMD;
// (2) A-fragments gathered DIRECTLY from global in MFMA layout (lane(quad,m16)
// loads its exact 16B: row seg/sdst[...m16], offset (k4&1)*32+quad*8) — kills
// the LDS staging round-trip AND both barriers (everything is wave-private:
// proj rows [wv*16,wv*16+16), scale_s/src_s slices, reduce). LDS = proj only
// (~18 KB -> 8 blocks/CU). Scatter atomics identical to R0 (proven fastest
// structure; they were NOT the binding constraint at 14 waves). --------------
__global__ __launch_bounds__(256, 8) void k_edge5(
    const unsigned short* __restrict__ xbf, const unsigned short* __restrict__ wT,
    const float* __restrict__ b, const int* __restrict__ sdst,
    const int* __restrict__ seg, const unsigned* __restrict__ cnt,
    const float* __restrict__ wgt, float* __restrict__ out) {
    const int t  = blockIdx.y;
    const int e0 = blockIdx.x * 64;

    __shared__ __align__(16) float proj[64][68];   // f32 proj, stride 68 (2-way banks)
    __shared__ float scale_s[64];
    __shared__ int   src_s[68];                    // padded

    const int tid = threadIdx.x;
    const int wv = tid >> 6, lane = tid & 63;
    const int m16 = lane & 15, quad = lane >> 4;
    const int row = wv * 16 + m16;                 // this lane's A-row (16/wave)

    // indices for A-row (4-way redundant across quads: coalesced broadcast)
    const size_t pos = (size_t)t * EE + e0 + row;
    const int srcI = seg[pos];
    const int dstI = sdst[pos];
    if (quad == 0) {
        src_s[row] = srcI;
        scale_s[row] = wgt[t] / (float)cnt[t * NN + srcI];
    }

    const unsigned short* wrow = wT + (size_t)t * 8192;   // [d][k], 64x128
    const unsigned short* arow_s = xbf + (size_t)srcI * 64;
    const unsigned short* arow_d = xbf + (size_t)dstI * 64;

    f32x4 acc[4];
#pragma unroll
    for (int tn = 0; tn < 4; tn++) acc[tn] = (f32x4){0.f, 0.f, 0.f, 0.f};

#pragma unroll
    for (int k4 = 0; k4 < 4; k4++) {
        // A fragment direct from global: feats row = [x[src](0..63) | x[dst](64..127)]
        const int off = (k4 & 1) * 32 + quad * 8;
        const bf16x8 af = *reinterpret_cast<const bf16x8*>((k4 < 2 ? arow_s : arow_d) + off);
        const int kb = k4 * 32 + quad * 8;
        bf16x8 bfr[4];
#pragma unroll
        for (int tn = 0; tn < 4; tn++)
            bfr[tn] = *reinterpret_cast<const bf16x8*>(wrow + (tn * 16 + m16) * 128 + kb);
#pragma unroll
        for (int tn = 0; tn < 4; tn++)
            acc[tn] = __builtin_amdgcn_mfma_f32_16x16x32_bf16(af, bfr[tn], acc[tn], 0, 0, 0);
    }

    float bias[4];
#pragma unroll
    for (int tn = 0; tn < 4; tn++) bias[tn] = b[t * 64 + tn * 16 + m16];

    // scale + relu -> proj (wave-private rows; same-wave LDS order via lgkmcnt)
#pragma unroll
    for (int r = 0; r < 4; r++) {
        const int eloc = wv * 16 + quad * 4 + r;
        const float s = scale_s[eloc];
#pragma unroll
        for (int tn = 0; tn < 4; tn++) {
            float v = acc[tn][r] + bias[tn];
            v = v > 0.f ? v : 0.f;
            proj[eloc][tn * 16 + m16] = v * s;
        }
    }

    // wave-cooperative segmented reduce: lane = feature, walk 16 sorted edges,
    // flush one COALESCED 256B atomic burst per segment (R0 verbatim, 16 rows).
    {
        const int j0 = wv * 16;
        float sum = 0.f;
#pragma unroll
        for (int j = j0; j < j0 + 16; j++) {
            sum += proj[j][lane];
            const bool flush = (j == j0 + 15) || (src_s[j + 1] != src_s[j]);
            if (flush) {
                atomicAdd(out + (size_t)src_s[j] * 64 + lane, sum);
                sum = 0.f;
            }
        }
    }
}

extern "C" void kernel_launch(void* const* d_in, const int* in_sizes, int n_in,
                              void* d_out, int out_size, void* d_ws, size_t ws_size,
                              hipStream_t stream) {
    const float* x     = (const float*)d_in[0];
    const float* W     = (const float*)d_in[1];
    const float* b     = (const float*)d_in[2];
    const float* ea    = (const float*)d_in[3];
    const int*   edges = (const int*)d_in[4];
    float* out = (float*)d_out;

    char* ws = (char*)d_ws;
    unsigned short* xbf  = (unsigned short*)(ws + OFF_XBF);
    unsigned short* wT   = (unsigned short*)(ws + OFF_WT);
    unsigned* cnt_tot    = (unsigned*)(ws + OFF_CTOT);
    float* wgt           = (float*)(ws + OFF_WGT);
    unsigned* cur        = (unsigned*)(ws + OFF_CUR);
    unsigned* bsum       = (unsigned*)(ws + OFF_BS);
    unsigned* boff       = (unsigned*)(ws + OFF_BO);
    unsigned* pe         = (unsigned*)(ws + OFF_PE);
    unsigned* pb         = (unsigned*)(ws + OFF_PB);
    int* sdst            = (int*)(ws + OFF_DST);
    int* seg             = (int*)(ws + OFF_SEG);

    // Phase 1: out-zero, x->bf16, W^T, softmax
    k_init<<<(NN * DD) / 256, 256, 0, stream>>>(x, W, ea, xbf, wT, wgt, out);

    // Phase 2: single-read partition sort (R2 pipeline, widened: CH 16->40)
    k_pcount<<<dim3(PSPLIT, TT), 256, 0, stream>>>(edges, pb);
    k_pscan<<<1, 512, 0, stream>>>(pb);
    k_pscat<<<dim3(PSPLIT, TT), 256, 0, stream>>>(edges, pb, pe);
    k_bcount<<<dim3(CH, TT), 512, 0, stream>>>(pe, pb, cnt_tot);
    k_scan1<<<SCAN_B, SCAN_T, 0, stream>>>(cnt_tot, cur, bsum);
    k_scan2<<<1, SCAN_B, 0, stream>>>(bsum, boff);
    k_bfill<<<dim3(CH, TT), 512, 0, stream>>>(pe, pb, cur, boff, cnt_tot, sdst, seg);

    // Phase 3: barrier-free direct-fragment MFMA gather + segmented scatter
    dim3 grid(EE / 64, TT);
    k_edge5<<<grid, 256, 0, stream>>>(xbf, wT, b, sdst, seg, cnt_tot, wgt, out);
}

// Round 7
// 320.178 us; speedup vs baseline: 1.5204x; 1.3077x over previous
//
#include <hip/hip_runtime.h>
#include <hip/hip_bf16.h>

#define NN 100000
#define DD 64
#define EE 400000
#define TT 5

#define CH 40                    /* coarse src buckets (chunks) */
#define BPC 2500                 /* NN/CH exact */
#define PSPLIT 32                /* partition slices per t */
#define PESL (EE / PSPLIT)       /* 12,500 edges per slice */
#define PBN (TT * CH * PSPLIT)   /* 6400 partition counters */
#define PB_IDX(t, c, s) ((((t) * CH + (c)) * PSPLIT) + (s))

#define SCAN_TOTAL 500000        /* T*N bins */
#define SCAN_T 256
#define SCAN_PER 1024            /* bins per scan block */
#define SCAN_B 512               /* 512*1024 >= 500000 */

typedef __bf16 bf16x8 __attribute__((ext_vector_type(8)));
typedef float  f32x4  __attribute__((ext_vector_type(4)));

// ws layout (bytes) — total 40,914,240 (unchanged envelope)
#define OFF_XBF  0u            // N*D ushort      = 12,800,000
#define OFF_WT   12800000u     // T*64*128 ushort = 81,920
#define OFF_CTOT 12881920u     // T*N u32 (cnt_tot) = 2,000,000
#define OFF_WGT  14881920u     // T f32 (pad 64)
#define OFF_CUR  14881984u     // T*N u32 (scan of totals) = 2,000,000
#define OFF_BS   16881984u     // 512 u32 (pad 2048)
#define OFF_BO   16884032u     // 512 u32 (pad 2048)
#define OFF_PE   16886080u     // 2M u32 packed (src_local<<17|dst) = 8,000,000
#define OFF_PB   24886080u     // 6401 u32 partition scan (25,604 B < 28,160 slack)
#define OFF_DST  24914240u     // 2M int (sorted dst) = 8,000,000
#define OFF_SEG  32914240u     // 2M int (seg src)    = 8,000,000 -> 40,914,240

__device__ __forceinline__ unsigned short f2bf(float f) {
    union { float f; unsigned u; } v; v.f = f;
    unsigned u = v.u;
    return (unsigned short)((u + 0x7FFFu + ((u >> 16) & 1u)) >> 16);  // RNE
}

// ---------------- Phase 1: init / convert / out-zero, FUSED with coarse
// 40-bucket partition counts (blocks 0..159 do both; all inputs read-only,
// pb consumed only by the NEXT launch -> stream-ordered). ---------------------
__global__ __launch_bounds__(256) void k_init(
        const float* __restrict__ x, const float* __restrict__ W,
        const float* __restrict__ ea, const int* __restrict__ edges,
        unsigned short* __restrict__ xbf, unsigned short* __restrict__ wT,
        float* __restrict__ wgt, float* __restrict__ out,
        unsigned* __restrict__ pcnt) {
    int i = blockIdx.x * blockDim.x + threadIdx.x;   // grid covers N*D exactly
    if (i < NN * DD) {
        out[i] = 0.0f;
        xbf[i] = f2bf(x[i]);
    }
    if (i < TT * 128 * 64) {
        int t = i >> 13;          // /8192
        int rem = i & 8191;
        int d = rem >> 7;         // /128
        int k = rem & 127;
        wT[i] = f2bf(W[t * 8192 + k * 64 + d]);   // wT[t][d][k] = W[t][k][d]
    }
    if (i == 0) {
        float m = -1e30f;
        for (int t = 0; t < TT; t++) m = fmaxf(m, ea[t]);
        float e[TT]; float s = 0.0f;
        for (int t = 0; t < TT; t++) { e[t] = __expf(ea[t] - m); s += e[t]; }
        for (int t = 0; t < TT; t++) wgt[t] = e[t] / s;
    }
    // fused pcount: 160 (slice, t) pairs on blocks 0..159 (block-uniform branch)
    if (blockIdx.x < PSPLIT * TT) {
        const int s = blockIdx.x & (PSPLIT - 1);
        const int t = blockIdx.x >> 5;               // PSPLIT == 32
        __shared__ unsigned h[CH];
        if (threadIdx.x < CH) h[threadIdx.x] = 0u;
        __syncthreads();
        const int4* srcp = reinterpret_cast<const int4*>(edges + (size_t)t * 2 * EE + s * PESL);
        for (int j = threadIdx.x; j < PESL / 4; j += 256) {
            int4 v = srcp[j];
            atomicAdd(&h[(unsigned)v.x / BPC], 1u);
            atomicAdd(&h[(unsigned)v.y / BPC], 1u);
            atomicAdd(&h[(unsigned)v.z / BPC], 1u);
            atomicAdd(&h[(unsigned)v.w / BPC], 1u);
        }
        __syncthreads();
        if (threadIdx.x < CH) pcnt[PB_IDX(t, threadIdx.x, s)] = h[threadIdx.x];
    }
}

// ---------------- Phase 2b: exclusive scan of 6400 partition counters --------
__global__ void k_pscan(unsigned* __restrict__ pb) {
    __shared__ unsigned s[512];
    const int tid = threadIdx.x;
    unsigned v[13]; unsigned sum = 0u;
#pragma unroll
    for (int j = 0; j < 13; j++) {
        int g = tid * 13 + j;
        v[j] = (g < PBN) ? pb[g] : 0u;
        sum += v[j];
    }
    s[tid] = sum;
    __syncthreads();
    unsigned inc = sum;
    for (int d = 1; d < 512; d <<= 1) {
        unsigned a = (tid >= d) ? s[tid - d] : 0u;
        __syncthreads();
        inc += a;
        s[tid] = inc;
        __syncthreads();
    }
    unsigned run = inc - sum;
#pragma unroll
    for (int j = 0; j < 13; j++) {
        int g = tid * 13 + j;
        if (g < PBN) pb[g] = run;
        run += v[j];
    }
    if (tid == 511) pb[PBN] = run;   // sentinel = 2,000,000
}

// ---------------- Phase 2c: partition scatter, (src_local:12 | dst:17) -------
__global__ __launch_bounds__(256) void k_pscat(const int* __restrict__ edges,
                                               const unsigned* __restrict__ pbase,
                                               unsigned* __restrict__ pe) {
    const int s = blockIdx.x, t = blockIdx.y;
    __shared__ unsigned lofs[CH];
    if (threadIdx.x < CH) lofs[threadIdx.x] = pbase[PB_IDX(t, threadIdx.x, s)];
    __syncthreads();
    const int* srcp = edges + (size_t)t * 2 * EE + s * PESL;
    const int* dstp = srcp + EE;
    for (int i = threadIdx.x; i < PESL / 4; i += 256) {
        int4 v = reinterpret_cast<const int4*>(srcp)[i];
        int4 w = reinterpret_cast<const int4*>(dstp)[i];
        {
            unsigned c = (unsigned)v.x / BPC;
            unsigned o = atomicAdd(&lofs[c], 1u);
            pe[o] = (((unsigned)v.x - c * BPC) << 17) | (unsigned)w.x;
        }
        {
            unsigned c = (unsigned)v.y / BPC;
            unsigned o = atomicAdd(&lofs[c], 1u);
            pe[o] = (((unsigned)v.y - c * BPC) << 17) | (unsigned)w.y;
        }
        {
            unsigned c = (unsigned)v.z / BPC;
            unsigned o = atomicAdd(&lofs[c], 1u);
            pe[o] = (((unsigned)v.z - c * BPC) << 17) | (unsigned)w.z;
        }
        {
            unsigned c = (unsigned)v.w / BPC;
            unsigned o = atomicAdd(&lofs[c], 1u);
            pe[o] = (((unsigned)v.w - c * BPC) << 17) | (unsigned)w.w;
        }
    }
}

// ---------------- Phase 2d: exact per-src counts from bucketed pe ------------
__global__ __launch_bounds__(512) void k_bcount(const unsigned* __restrict__ pe,
                                                const unsigned* __restrict__ pbase,
                                                unsigned* __restrict__ cnt_tot) {
    const int c = blockIdx.x, t = blockIdx.y;
    __shared__ unsigned h[BPC];
    for (int i = threadIdx.x; i < BPC; i += 512) h[i] = 0u;
    __syncthreads();
    const unsigned st = pbase[PB_IDX(t, c, 0)];
    const unsigned en = pbase[((t * CH + c) + 1) * PSPLIT];
    for (unsigned i = st + threadIdx.x; i < en; i += 512)
        atomicAdd(&h[pe[i] >> 17], 1u);
    __syncthreads();
    unsigned* outp = cnt_tot + t * NN + c * BPC;
    for (int i = threadIdx.x; i < BPC; i += 512) outp[i] = h[i];
}

// ---------------- Phase 2e: global exclusive scan over T*N bins --------------
__global__ void k_scan1(const unsigned* __restrict__ cnt_tot,
                        unsigned* __restrict__ cur, unsigned* __restrict__ bsum) {
    __shared__ unsigned s[SCAN_T];
    const int b = blockIdx.x, tid = threadIdx.x;
    const int base = b * SCAN_PER + tid * 4;
    unsigned tot[4] = {0u, 0u, 0u, 0u};
    if (base < SCAN_TOTAL) {
        uint4 tv = *reinterpret_cast<const uint4*>(cnt_tot + base);
        tot[0] = tv.x; tot[1] = tv.y; tot[2] = tv.z; tot[3] = tv.w;
    }
    const unsigned tsum = tot[0] + tot[1] + tot[2] + tot[3];
    s[tid] = tsum;
    __syncthreads();
    unsigned inc = tsum;
    for (int d = 1; d < SCAN_T; d <<= 1) {
        unsigned add = (tid >= d) ? s[tid - d] : 0u;
        __syncthreads();
        inc += add;
        s[tid] = inc;
        __syncthreads();
    }
    if (tid == SCAN_T - 1) bsum[b] = inc;
    const unsigned p0 = inc - tsum;
    if (base < SCAN_TOTAL) {
        *reinterpret_cast<uint4*>(cur + base) =
            make_uint4(p0, p0 + tot[0], p0 + tot[0] + tot[1], p0 + tot[0] + tot[1] + tot[2]);
    }
}

__global__ void k_scan2(const unsigned* __restrict__ bsum, unsigned* __restrict__ boff) {
    __shared__ unsigned s[SCAN_B];
    const int tid = threadIdx.x;
    const unsigned v = bsum[tid];
    s[tid] = v;
    __syncthreads();
    unsigned inc = v;
    for (int d = 1; d < SCAN_B; d <<= 1) {
        unsigned add = (tid >= d) ? s[tid - d] : 0u;
        __syncthreads();
        inc += add;
        s[tid] = inc;
        __syncthreads();
    }
    boff[tid] = inc - v;
}

// ---------------- Phase 2f: counting-sort fill + fused seg write -------------
__global__ __launch_bounds__(512) void k_bfill(const unsigned* __restrict__ pe,
                                               const unsigned* __restrict__ pbase,
                                               const unsigned* __restrict__ cur,
                                               const unsigned* __restrict__ boff,
                                               const unsigned* __restrict__ cnt_tot,
                                               int* __restrict__ sdst,
                                               int* __restrict__ seg) {
    const int c = blockIdx.x, t = blockIdx.y;
    __shared__ unsigned curl[BPC];
    const int n0 = c * BPC;
    for (int i = threadIdx.x; i < BPC; i += 512) {
        int g = t * NN + n0 + i;
        unsigned start = cur[g] + boff[g >> 10];
        curl[i] = start;
        unsigned cc = cnt_tot[g];
        int node = n0 + i;
        for (unsigned j = 0; j < cc; j++) seg[start + j] = node;
    }
    __syncthreads();
    const unsigned st = pbase[PB_IDX(t, c, 0)];
    const unsigned en = pbase[((t * CH + c) + 1) * PSPLIT];
    for (unsigned i = st + threadIdx.x; i < en; i += 512) {
        unsigned p = pe[i];
        sdst[atomicAdd(&curl[p >> 17], 1u)] = (int)(p & 0x1FFFFu);
    }
}

// ---------------- Phase 3: gather -> MFMA -> wave-cooperative segmented scatter.
// EXACT R0 kernel — proven 184.3 +/- 0.5 us across three reproductions.
// Deviations tried and REVERTED: exclusive ownership (R1: 386, R5: 340),
// global-atomic fill (R3), 2x occupancy + direct-fragment gather (R6: 282,
// occupancy 87% — proved phase 3 is atomic-stream-bound, not wave-starved). --
__global__ __launch_bounds__(256) void k_edge(
    const unsigned short* __restrict__ xbf, const unsigned short* __restrict__ wT,
    const float* __restrict__ b, const int* __restrict__ sdst,
    const int* __restrict__ seg, const unsigned* __restrict__ cnt,
    const float* __restrict__ wgt, float* __restrict__ out) {
    const int t  = blockIdx.y;
    const int e0 = blockIdx.x * 128;

    __shared__ __align__(16) unsigned short Ab[128][136];   // feats tile; reused as f32 proj[128][68]
    __shared__ float scale_s[128];
    __shared__ int   src_s[132];                             // padded

    const int tid = threadIdx.x;

    // stage A: gather x rows (bf16, 128B each); thread pair per sorted edge
    {
        int e = tid >> 1, half = tid & 1;
        size_t pos = (size_t)t * EE + e0 + e;
        int idx = half ? sdst[pos] : seg[pos];
        const float4* g = reinterpret_cast<const float4*>(xbf + (size_t)idx * 64);
        float4* l = reinterpret_cast<float4*>(&Ab[e][half * 64]);
#pragma unroll
        for (int c = 0; c < 8; c++) l[c] = g[c];
        if (half == 0) {
            src_s[e] = idx;
            scale_s[e] = wgt[t] / (float)cnt[t * NN + idx];   // cnt_tot table is L2-hot
        }
    }
    __syncthreads();

    const int wv = tid >> 6, lane = tid & 63;
    const int m16 = lane & 15, quad = lane >> 4;
    const unsigned short* wrow = wT + (size_t)t * 8192;      // [d][k], 64x128

    f32x4 acc[2][4];
#pragma unroll
    for (int tm = 0; tm < 2; tm++)
#pragma unroll
        for (int tn = 0; tn < 4; tn++)
            acc[tm][tn] = (f32x4){0.f, 0.f, 0.f, 0.f};

#pragma unroll
    for (int kk = 0; kk < 128; kk += 32) {
        const int kb = kk + quad * 8;
        bf16x8 af[2], bfr[4];
#pragma unroll
        for (int tm = 0; tm < 2; tm++)
            af[tm] = *reinterpret_cast<const bf16x8*>(&Ab[wv * 32 + tm * 16 + m16][kb]);
#pragma unroll
        for (int tn = 0; tn < 4; tn++)
            bfr[tn] = *reinterpret_cast<const bf16x8*>(wrow + (tn * 16 + m16) * 128 + kb);
#pragma unroll
        for (int tm = 0; tm < 2; tm++)
#pragma unroll
            for (int tn = 0; tn < 4; tn++)
                acc[tm][tn] = __builtin_amdgcn_mfma_f32_16x16x32_bf16(
                    af[tm], bfr[tn], acc[tm][tn], 0, 0, 0);
    }

    // all waves done reading Ab before we overwrite it with f32 proj
    __syncthreads();

    float bias[4];
#pragma unroll
    for (int tn = 0; tn < 4; tn++) bias[tn] = b[t * 64 + tn * 16 + m16];

    float* proj = reinterpret_cast<float*>(&Ab[0][0]);   // [128][68] f32, stride 68
#pragma unroll
    for (int tm = 0; tm < 2; tm++) {
#pragma unroll
        for (int r = 0; r < 4; r++) {
            const int eloc = wv * 32 + tm * 16 + quad * 4 + r;   // in [wv*32, wv*32+32)
            const float s = scale_s[eloc];
#pragma unroll
            for (int tn = 0; tn < 4; tn++) {
                float v = acc[tm][tn][r] + bias[tn];
                v = v > 0.f ? v : 0.f;
                proj[eloc * 68 + tn * 16 + m16] = v * s;
            }
        }
    }
    // NO barrier: wave wv wrote exactly proj rows [wv*32, wv*32+32) and reads
    // only those below. (src_s/scale_s were synced by the earlier barrier.)

    // wave-cooperative segmented reduce: lane = feature, walk 32 sorted edges,
    // flush one COALESCED 256B atomic burst per segment.
    {
        const int j0 = wv * 32;
        float sum = 0.f;
#pragma unroll
        for (int j = j0; j < j0 + 32; j++) {
            sum += proj[j * 68 + lane];
            const bool flush = (j == j0 + 31) || (src_s[j + 1] != src_s[j]);
            if (flush) {
                atomicAdd(out + (size_t)src_s[j] * 64 + lane, sum);
                sum = 0.f;
            }
        }
    }
}

extern "C" void kernel_launch(void* const* d_in, const int* in_sizes, int n_in,
                              void* d_out, int out_size, void* d_ws, size_t ws_size,
                              hipStream_t stream) {
    const float* x     = (const float*)d_in[0];
    const float* W     = (const float*)d_in[1];
    const float* b     = (const float*)d_in[2];
    const float* ea    = (const float*)d_in[3];
    const int*   edges = (const int*)d_in[4];
    float* out = (float*)d_out;

    char* ws = (char*)d_ws;
    unsigned short* xbf  = (unsigned short*)(ws + OFF_XBF);
    unsigned short* wT   = (unsigned short*)(ws + OFF_WT);
    unsigned* cnt_tot    = (unsigned*)(ws + OFF_CTOT);
    float* wgt           = (float*)(ws + OFF_WGT);
    unsigned* cur        = (unsigned*)(ws + OFF_CUR);
    unsigned* bsum       = (unsigned*)(ws + OFF_BS);
    unsigned* boff       = (unsigned*)(ws + OFF_BO);
    unsigned* pe         = (unsigned*)(ws + OFF_PE);
    unsigned* pb         = (unsigned*)(ws + OFF_PB);
    int* sdst            = (int*)(ws + OFF_DST);
    int* seg             = (int*)(ws + OFF_SEG);

    // Phase 1: out-zero, x->bf16, W^T, softmax + FUSED partition counts
    k_init<<<(NN * DD) / 256, 256, 0, stream>>>(x, W, ea, edges, xbf, wT, wgt, out, pb);

    // Phase 2: single-read partition sort (widened CH=40, R6-proven)
    k_pscan<<<1, 512, 0, stream>>>(pb);
    k_pscat<<<dim3(PSPLIT, TT), 256, 0, stream>>>(edges, pb, pe);
    k_bcount<<<dim3(CH, TT), 512, 0, stream>>>(pe, pb, cnt_tot);
    k_scan1<<<SCAN_B, SCAN_T, 0, stream>>>(cnt_tot, cur, bsum);
    k_scan2<<<1, SCAN_B, 0, stream>>>(bsum, boff);
    k_bfill<<<dim3(CH, TT), 512, 0, stream>>>(pe, pb, cur, boff, cnt_tot, sdst, seg);

    // Phase 3: MFMA gather-GEMM + wave-cooperative segmented scatter (R0 proven)
    dim3 grid(EE / 128, TT);
    k_edge<<<grid, 256, 0, stream>>>(xbf, wT, b, sdst, seg, cnt_tot, wgt, out);
}